// Round 17
// baseline (833.264 us; speedup 1.0000x reference)
//
#include <hip/hip_runtime.h>
#include <float.h>

// Tropical (max-plus) linear: y[b,o] = max_i (x[b,i] + W[o,i])
// B=512, I=1024, O=1024, fp32. No MFMA (max-plus) -> fp32 VALU.
//
// Round-17 = round-15 (best: 86.9 us; barrier-free wave-private tiles,
// scalar fp32 body, fp16 slabs) + TRIPLE-buffered staging (prefetch
// distance 2). r16 disproved issue-count as the binding constraint
// (fp16 packed asm = half the instrs = slightly WORSE); the remaining
// candidate for main's ~9 us over its 20.4 us issue floor is DMA-latency
// exposure: distance-1 prefetch gives ~770-1500 cyc cover vs 200-900 cyc
// global_load_lds latency. Distance 2 doubles the cover at zero codegen
// change. LDS 3 bufs x 5 KB x 4 waves = 60 KB/block, 2 blocks/CU = 120 KB.
//  CODEGEN RULE (r5/r7/r9/r12 demotions; r16 asm regression): pure scalar
//  fp32 dataflow in the hot loop; float4/uint2/uint4 only as named
//  immediate load/store temps; no inline asm.

#define B_DIM 512
#define I_DIM 1024
#define O_DIM 1024
#define KT 8             // k per staged chunk

__device__ __forceinline__ void g2lds16(const float* g, float* l) {
    __builtin_amdgcn_global_load_lds(
        (const __attribute__((address_space(1))) void*)g,
        (__attribute__((address_space(3))) void*)l, 16, 0, 0);
}

// scalar fp16 helpers (r13/r15-proven clean codegen)
__device__ __forceinline__ unsigned pack2h(float a, float b) {
    const unsigned lo = (unsigned)__builtin_bit_cast(unsigned short, (_Float16)a);
    const unsigned hi = (unsigned)__builtin_bit_cast(unsigned short, (_Float16)b);
    return lo | (hi << 16);
}
__device__ __forceinline__ float lo16f(unsigned u) {
    return (float)__builtin_bit_cast(_Float16, (unsigned short)(u & 0xffffu));
}
__device__ __forceinline__ float hi16f(unsigned u) {
    return (float)__builtin_bit_cast(_Float16, (unsigned short)(u >> 16));
}

template <int KB>   // k handled per block
__global__ __launch_bounds__(256, 2) void trop_main(
    const float* __restrict__ xT,    // [I_DIM][B_DIM]
    const float* __restrict__ wT,    // [I_DIM][O_DIM]
    _Float16* __restrict__ part)     // [KSPLIT][B_DIM][O_DIM] fp16 slabs
{
    constexpr int NCH = KB / KT;
    static_assert(KB % KT == 0 && NCH >= 2, "");
    __shared__ __align__(16) float xs[4][3][KT * 32];    // [wave][buf][k][b32]
    __shared__ __align__(16) float ws[4][3][KT * 128];   // [wave][buf][k][o]

    const int tid  = threadIdx.x;
    const int wave = tid >> 6;          // 0..3: owns b-rows [32*wave, +32)
    const int lane = tid & 63;
    const int to   = lane & 15;         // o-quad selector (0..15)
    const int tbw  = lane >> 4;         // b-quad selector within wave (0..3)
    const int o0 = blockIdx.x * 128;
    const int bw0 = blockIdx.y * 128 + 32 * wave;
    const int kz = blockIdx.z;
    const int kbase = kz * KB;

    const int rk8 = lane >> 3;          // x DMA: k-row 0..7
    const int xc4 = (lane & 7) * 4;     //        b-col (floats)
    const int rk2 = lane >> 5;          // w DMA: k-subrow 0..1
    const int wc4 = (lane & 31) * 4;    //        o-col (floats)

    float acc[8][8];                    // SCALAR regs — the only clean form
    #pragma unroll
    for (int i = 0; i < 8; ++i)
        #pragma unroll
        for (int j = 0; j < 8; ++j)
            acc[i][j] = -FLT_MAX;

    auto stage = [&](int c, int buf) {
        const int k0 = kbase + c * KT;
        g2lds16(&xT[(size_t)(k0 + rk8) * B_DIM + bw0 + xc4],
                &xs[wave][buf][0]);
        #pragma unroll
        for (int t = 0; t < 4; ++t)
            g2lds16(&wT[(size_t)(k0 + 2 * t + rk2) * O_DIM + o0 + wc4],
                    &ws[wave][buf][t * 256]);
    };

    auto compute = [&](int buf) {
        const float* xB = &xs[wave][buf][4 * tbw];   // static imm offsets
        const float* wB = &ws[wave][buf][4 * to];
        #pragma unroll                                // 4 k-pairs
        for (int k = 0; k < KT; k += 2) {
            const float4 xa0 = *(const float4*)&xB[k * 32];
            const float4 xa1 = *(const float4*)&xB[k * 32 + 16];
            const float4 xb0 = *(const float4*)&xB[(k + 1) * 32];
            const float4 xb1 = *(const float4*)&xB[(k + 1) * 32 + 16];
            const float4 wa0 = *(const float4*)&wB[k * 128];
            const float4 wa1 = *(const float4*)&wB[k * 128 + 64];
            const float4 wb0 = *(const float4*)&wB[(k + 1) * 128];
            const float4 wb1 = *(const float4*)&wB[(k + 1) * 128 + 64];

            const float xa[8] = {xa0.x, xa0.y, xa0.z, xa0.w, xa1.x, xa1.y, xa1.z, xa1.w};
            const float xb[8] = {xb0.x, xb0.y, xb0.z, xb0.w, xb1.x, xb1.y, xb1.z, xb1.w};
            const float wa[8] = {wa0.x, wa0.y, wa0.z, wa0.w, wa1.x, wa1.y, wa1.z, wa1.w};
            const float wb[8] = {wb0.x, wb0.y, wb0.z, wb0.w, wb1.x, wb1.y, wb1.z, wb1.w};

            #pragma unroll
            for (int i = 0; i < 8; ++i)
                #pragma unroll
                for (int j = 0; j < 8; ++j) {
                    const float s0 = xa[i] + wa[j];
                    const float s1 = xb[i] + wb[j];
                    acc[i][j] = fmaxf(acc[i][j], fmaxf(s0, s1));   // v_max3_f32
                }
        }
    };

    // barrier-free, triple-buffered: stage c+2 while computing c
    stage(0, 0);
    stage(1, 1);
    #pragma unroll
    for (int c = 0; c < NCH; ++c) {
        if (c + 2 < NCH) stage(c + 2, (c + 2) % 3);   // compile-time buf
        compute(c % 3);
    }

    // epilogue: pack to fp16 (scalar cvt+or), uint2 stores into fp16 slab
    _Float16* pout = part + (size_t)kz * (B_DIM * O_DIM);
    #pragma unroll
    for (int i = 0; i < 8; ++i) {
        const int b = bw0 + (i >> 2) * 16 + 4 * tbw + (i & 3);
        const uint2 v0 = make_uint2(pack2h(acc[i][0], acc[i][1]),
                                    pack2h(acc[i][2], acc[i][3]));
        const uint2 v1 = make_uint2(pack2h(acc[i][4], acc[i][5]),
                                    pack2h(acc[i][6], acc[i][7]));
        *(uint2*)((char*)pout + ((size_t)b * O_DIM + o0 + 4 * to) * 2)      = v0;
        *(uint2*)((char*)pout + ((size_t)b * O_DIM + o0 + 64 + 4 * to) * 2) = v1;
    }
}

// ---- fused transpose: z=0 -> xT from x (512x1024); z=1,2 -> wT halves
__global__ __launch_bounds__(256) void transpose3(
    const float* __restrict__ x, float* __restrict__ xT,
    const float* __restrict__ W, float* __restrict__ wT)
{
    __shared__ float tile[32][33];
    const int tx = threadIdx.x;   // 0..31
    const int ty = threadIdx.y;   // 0..7
    const int z  = blockIdx.z;
    const float* in; float* out; int dst_ld;
    if (z == 0) { in = x;                  out = xT;            dst_ld = B_DIM; }
    else        { in = W + (size_t)(z - 1) * 512 * I_DIM;
                  out = wT + (z - 1) * 512;                     dst_ld = O_DIM; }
    const int r0 = blockIdx.y * 32;
    const int c0 = blockIdx.x * 32;
    #pragma unroll
    for (int i = 0; i < 4; ++i)
        tile[ty + 8 * i][tx] = in[(size_t)(r0 + ty + 8 * i) * I_DIM + c0 + tx];
    __syncthreads();
    #pragma unroll
    for (int i = 0; i < 4; ++i)
        out[(size_t)(c0 + ty + 8 * i) * dst_ld + r0 + tx] = tile[tx][ty + 8 * i];
}

// ---- reduce fp16 slabs -> fp32 y (r15-verified)
template <int KS>
__global__ __launch_bounds__(256) void trop_reduce_h(
    const _Float16* __restrict__ part, float* __restrict__ y)
{
    constexpr size_t N = (size_t)B_DIM * O_DIM;    // halves per slab
    const int idx = blockIdx.x * 256 + threadIdx.x;
    float m0 = -FLT_MAX, m1 = -FLT_MAX, m2 = -FLT_MAX, m3 = -FLT_MAX;
    float m4 = -FLT_MAX, m5 = -FLT_MAX, m6 = -FLT_MAX, m7 = -FLT_MAX;
    #pragma unroll
    for (int s = 0; s < KS; ++s) {
        const uint4 v = *(const uint4*)((const char*)part + (s * N + (size_t)idx * 8) * 2);
        m0 = fmaxf(m0, lo16f(v.x)); m1 = fmaxf(m1, hi16f(v.x));
        m2 = fmaxf(m2, lo16f(v.y)); m3 = fmaxf(m3, hi16f(v.y));
        m4 = fmaxf(m4, lo16f(v.z)); m5 = fmaxf(m5, hi16f(v.z));
        m6 = fmaxf(m6, lo16f(v.w)); m7 = fmaxf(m7, hi16f(v.w));
    }
    const float4 o0 = make_float4(m0, m1, m2, m3);
    const float4 o1 = make_float4(m4, m5, m6, m7);
    ((float4*)y)[2 * idx]     = o0;
    ((float4*)y)[2 * idx + 1] = o1;
}

// correctness-net fallback if d_ws is tiny (fp32, exact)
__global__ __launch_bounds__(256) void trop_naive(
    const float* __restrict__ x, const float* __restrict__ W,
    float* __restrict__ y)
{
    const int idx = blockIdx.x * 256 + threadIdx.x;
    const int b = idx / O_DIM, o = idx % O_DIM;
    float m = -FLT_MAX;
    for (int i = 0; i < I_DIM; ++i)
        m = fmaxf(m, x[b * I_DIM + i] + W[o * I_DIM + i]);
    y[idx] = m;
}

extern "C" void kernel_launch(void* const* d_in, const int* in_sizes, int n_in,
                              void* d_out, int out_size, void* d_ws, size_t ws_size,
                              hipStream_t stream) {
    const float* x = (const float*)d_in[0];
    const float* W = (const float*)d_in[1];
    float* y = (float*)d_out;

    const size_t slab_h = (size_t)B_DIM * O_DIM * 2;              // 1 MB fp16
    const size_t xT_sz  = (size_t)B_DIM * I_DIM * sizeof(float);  // 2 MB
    const size_t wT_sz  = (size_t)O_DIM * I_DIM * sizeof(float);  // 4 MB
    const dim3 rgrid(B_DIM * O_DIM / 8 / 256);                    // 256 blocks
    const dim3 tgrid(I_DIM / 32, 512 / 32, 3);
    const dim3 tblk(32, 8);

    if (ws_size >= 16 * slab_h + xT_sz + wT_sz) {        // 22 MB
        _Float16* part = (_Float16*)d_ws;
        float* xT = (float*)((char*)d_ws + 16 * slab_h);
        float* wT = xT + (size_t)B_DIM * I_DIM;
        transpose3<<<tgrid, tblk, 0, stream>>>(x, xT, W, wT);
        trop_main<I_DIM / 16><<<dim3(8, 4, 16), 256, 0, stream>>>(xT, wT, part);
        trop_reduce_h<16><<<rgrid, 256, 0, stream>>>(part, y);
    } else if (ws_size >= 8 * slab_h + xT_sz + wT_sz) {  // 14 MB
        _Float16* part = (_Float16*)d_ws;
        float* xT = (float*)((char*)d_ws + 8 * slab_h);
        float* wT = xT + (size_t)B_DIM * I_DIM;
        transpose3<<<tgrid, tblk, 0, stream>>>(x, xT, W, wT);
        trop_main<I_DIM / 8><<<dim3(8, 4, 8), 256, 0, stream>>>(xT, wT, part);
        trop_reduce_h<8><<<rgrid, 256, 0, stream>>>(part, y);
    } else if (ws_size >= slab_h + xT_sz + wT_sz) {      // 7 MB: no K-split
        _Float16* part = (_Float16*)d_ws;
        float* xT = (float*)((char*)d_ws + slab_h);
        float* wT = xT + (size_t)B_DIM * I_DIM;
        transpose3<<<tgrid, tblk, 0, stream>>>(x, xT, W, wT);
        trop_main<I_DIM><<<dim3(8, 4, 1), 256, 0, stream>>>(xT, wT, part);
        trop_reduce_h<1><<<rgrid, 256, 0, stream>>>(part, y);
    } else {
        trop_naive<<<dim3(B_DIM * O_DIM / 256), 256, 0, stream>>>(x, W, y);
    }
}

// Round 18
// 86.795 us; speedup vs baseline: 9.6004x; 9.6004x over previous
//
#include <hip/hip_runtime.h>
#include <float.h>

// Tropical (max-plus) linear: y[b,o] = max_i (x[b,i] + W[o,i])
// B=512, I=1024, O=1024, fp32. No MFMA (max-plus) -> fp32 VALU.
//
// FINAL (= round-15, session best 86.9 us): barrier-free wave-private
// double-buffered LDS tiles + scalar fp32 compute + fp16 K-split slabs.
//  * Main K-loop: pinned at ~29-30 us = 1.45x the 20.4 us dual-pipe issue
//    floor (LDS 10.2 + VALU 10.2). Invariant under occupancy (1-4 waves/SIMD),
//    barrier granularity/removal, prefetch depth, unroll shape, instruction
//    count (fp16 packed asm = half the instrs = WORSE, r16). Both pipes
//    ~100% demand; residual is issue-port friction. Stop.
//  * 6 demotion detonations (r5 f32x4, r7 f32x2 arr, r9 named f32x2,
//    r12 half2v, r17 triple-buffer): ONLY this exact form compiles clean —
//    pure scalar fp32 register state, float4/uint2 as named immediate
//    load/store temps, 2 LDS buffers, no inline asm.
//  * fp16 slabs: absmax 0.031 << 0.1625 tolerance; halves slab traffic.
//  * dur_us ledger: ~48 us fixed harness poison/restore fills (262 MB @
//    6.6 TB/s, outside kernel control) + ~2.5 transpose + ~29 main +
//    ~2.5 reduce + launch gaps.

#define B_DIM 512
#define I_DIM 1024
#define O_DIM 1024
#define KT 8             // k per staged chunk

__device__ __forceinline__ void g2lds16(const float* g, float* l) {
    __builtin_amdgcn_global_load_lds(
        (const __attribute__((address_space(1))) void*)g,
        (__attribute__((address_space(3))) void*)l, 16, 0, 0);
}

// scalar fp16 helpers (r13/r15-proven clean codegen)
__device__ __forceinline__ unsigned pack2h(float a, float b) {
    const unsigned lo = (unsigned)__builtin_bit_cast(unsigned short, (_Float16)a);
    const unsigned hi = (unsigned)__builtin_bit_cast(unsigned short, (_Float16)b);
    return lo | (hi << 16);
}
__device__ __forceinline__ float lo16f(unsigned u) {
    return (float)__builtin_bit_cast(_Float16, (unsigned short)(u & 0xffffu));
}
__device__ __forceinline__ float hi16f(unsigned u) {
    return (float)__builtin_bit_cast(_Float16, (unsigned short)(u >> 16));
}

template <int KB>   // k handled per block
__global__ __launch_bounds__(256, 2) void trop_main(
    const float* __restrict__ xT,    // [I_DIM][B_DIM]
    const float* __restrict__ wT,    // [I_DIM][O_DIM]
    _Float16* __restrict__ part)     // [KSPLIT][B_DIM][O_DIM] fp16 slabs
{
    constexpr int NCH = KB / KT;
    static_assert(KB % KT == 0, "");
    __shared__ __align__(16) float xs[4][2][KT * 32];    // [wave][buf][k][b32]
    __shared__ __align__(16) float ws[4][2][KT * 128];   // [wave][buf][k][o]

    const int tid  = threadIdx.x;
    const int wave = tid >> 6;          // 0..3: owns b-rows [32*wave, +32)
    const int lane = tid & 63;
    const int to   = lane & 15;         // o-quad selector (0..15)
    const int tbw  = lane >> 4;         // b-quad selector within wave (0..3)
    const int o0 = blockIdx.x * 128;
    const int bw0 = blockIdx.y * 128 + 32 * wave;
    const int kz = blockIdx.z;
    const int kbase = kz * KB;

    const int rk8 = lane >> 3;          // x DMA: k-row 0..7
    const int xc4 = (lane & 7) * 4;     //        b-col (floats)
    const int rk2 = lane >> 5;          // w DMA: k-subrow 0..1
    const int wc4 = (lane & 31) * 4;    //        o-col (floats)

    float acc[8][8];                    // SCALAR regs — the only clean form
    #pragma unroll
    for (int i = 0; i < 8; ++i)
        #pragma unroll
        for (int j = 0; j < 8; ++j)
            acc[i][j] = -FLT_MAX;

    auto stage = [&](int c, int buf) {
        const int k0 = kbase + c * KT;
        g2lds16(&xT[(size_t)(k0 + rk8) * B_DIM + bw0 + xc4],
                &xs[wave][buf][0]);
        #pragma unroll
        for (int t = 0; t < 4; ++t)
            g2lds16(&wT[(size_t)(k0 + 2 * t + rk2) * O_DIM + o0 + wc4],
                    &ws[wave][buf][t * 256]);
    };

    auto compute = [&](int buf) {
        const float* xB = &xs[wave][buf][4 * tbw];   // static imm offsets
        const float* wB = &ws[wave][buf][4 * to];
        #pragma unroll                                // 4 k-pairs
        for (int k = 0; k < KT; k += 2) {
            const float4 xa0 = *(const float4*)&xB[k * 32];
            const float4 xa1 = *(const float4*)&xB[k * 32 + 16];
            const float4 xb0 = *(const float4*)&xB[(k + 1) * 32];
            const float4 xb1 = *(const float4*)&xB[(k + 1) * 32 + 16];
            const float4 wa0 = *(const float4*)&wB[k * 128];
            const float4 wa1 = *(const float4*)&wB[k * 128 + 64];
            const float4 wb0 = *(const float4*)&wB[(k + 1) * 128];
            const float4 wb1 = *(const float4*)&wB[(k + 1) * 128 + 64];

            const float xa[8] = {xa0.x, xa0.y, xa0.z, xa0.w, xa1.x, xa1.y, xa1.z, xa1.w};
            const float xb[8] = {xb0.x, xb0.y, xb0.z, xb0.w, xb1.x, xb1.y, xb1.z, xb1.w};
            const float wa[8] = {wa0.x, wa0.y, wa0.z, wa0.w, wa1.x, wa1.y, wa1.z, wa1.w};
            const float wb[8] = {wb0.x, wb0.y, wb0.z, wb0.w, wb1.x, wb1.y, wb1.z, wb1.w};

            #pragma unroll
            for (int i = 0; i < 8; ++i)
                #pragma unroll
                for (int j = 0; j < 8; ++j) {
                    const float s0 = xa[i] + wa[j];
                    const float s1 = xb[i] + wb[j];
                    acc[i][j] = fmaxf(acc[i][j], fmaxf(s0, s1));   // v_max3_f32
                }
        }
    };

    // barrier-free pipeline: wave-private buffers, compiler vmcnt only
    stage(0, 0);
    #pragma unroll
    for (int c = 0; c < NCH; ++c) {
        if (c + 1 < NCH) stage(c + 1, (c + 1) & 1);
        compute(c & 1);
    }

    // epilogue: pack to fp16 (scalar cvt+or), uint2 stores into fp16 slab
    _Float16* pout = part + (size_t)kz * (B_DIM * O_DIM);
    #pragma unroll
    for (int i = 0; i < 8; ++i) {
        const int b = bw0 + (i >> 2) * 16 + 4 * tbw + (i & 3);
        const uint2 v0 = make_uint2(pack2h(acc[i][0], acc[i][1]),
                                    pack2h(acc[i][2], acc[i][3]));
        const uint2 v1 = make_uint2(pack2h(acc[i][4], acc[i][5]),
                                    pack2h(acc[i][6], acc[i][7]));
        *(uint2*)((char*)pout + ((size_t)b * O_DIM + o0 + 4 * to) * 2)      = v0;
        *(uint2*)((char*)pout + ((size_t)b * O_DIM + o0 + 64 + 4 * to) * 2) = v1;
    }
}

// ---- fused transpose: z=0 -> xT from x (512x1024); z=1,2 -> wT halves
__global__ __launch_bounds__(256) void transpose3(
    const float* __restrict__ x, float* __restrict__ xT,
    const float* __restrict__ W, float* __restrict__ wT)
{
    __shared__ float tile[32][33];
    const int tx = threadIdx.x;   // 0..31
    const int ty = threadIdx.y;   // 0..7
    const int z  = blockIdx.z;
    const float* in; float* out; int dst_ld;
    if (z == 0) { in = x;                  out = xT;            dst_ld = B_DIM; }
    else        { in = W + (size_t)(z - 1) * 512 * I_DIM;
                  out = wT + (z - 1) * 512;                     dst_ld = O_DIM; }
    const int r0 = blockIdx.y * 32;
    const int c0 = blockIdx.x * 32;
    #pragma unroll
    for (int i = 0; i < 4; ++i)
        tile[ty + 8 * i][tx] = in[(size_t)(r0 + ty + 8 * i) * I_DIM + c0 + tx];
    __syncthreads();
    #pragma unroll
    for (int i = 0; i < 4; ++i)
        out[(size_t)(c0 + ty + 8 * i) * dst_ld + r0 + tx] = tile[tx][ty + 8 * i];
}

// ---- reduce fp16 slabs -> fp32 y (r15-verified)
template <int KS>
__global__ __launch_bounds__(256) void trop_reduce_h(
    const _Float16* __restrict__ part, float* __restrict__ y)
{
    constexpr size_t N = (size_t)B_DIM * O_DIM;    // halves per slab
    const int idx = blockIdx.x * 256 + threadIdx.x;
    float m0 = -FLT_MAX, m1 = -FLT_MAX, m2 = -FLT_MAX, m3 = -FLT_MAX;
    float m4 = -FLT_MAX, m5 = -FLT_MAX, m6 = -FLT_MAX, m7 = -FLT_MAX;
    #pragma unroll
    for (int s = 0; s < KS; ++s) {
        const uint4 v = *(const uint4*)((const char*)part + (s * N + (size_t)idx * 8) * 2);
        m0 = fmaxf(m0, lo16f(v.x)); m1 = fmaxf(m1, hi16f(v.x));
        m2 = fmaxf(m2, lo16f(v.y)); m3 = fmaxf(m3, hi16f(v.y));
        m4 = fmaxf(m4, lo16f(v.z)); m5 = fmaxf(m5, hi16f(v.z));
        m6 = fmaxf(m6, lo16f(v.w)); m7 = fmaxf(m7, hi16f(v.w));
    }
    const float4 o0 = make_float4(m0, m1, m2, m3);
    const float4 o1 = make_float4(m4, m5, m6, m7);
    ((float4*)y)[2 * idx]     = o0;
    ((float4*)y)[2 * idx + 1] = o1;
}

// correctness-net fallback if d_ws is tiny (fp32, exact)
__global__ __launch_bounds__(256) void trop_naive(
    const float* __restrict__ x, const float* __restrict__ W,
    float* __restrict__ y)
{
    const int idx = blockIdx.x * 256 + threadIdx.x;
    const int b = idx / O_DIM, o = idx % O_DIM;
    float m = -FLT_MAX;
    for (int i = 0; i < I_DIM; ++i)
        m = fmaxf(m, x[b * I_DIM + i] + W[o * I_DIM + i]);
    y[idx] = m;
}

extern "C" void kernel_launch(void* const* d_in, const int* in_sizes, int n_in,
                              void* d_out, int out_size, void* d_ws, size_t ws_size,
                              hipStream_t stream) {
    const float* x = (const float*)d_in[0];
    const float* W = (const float*)d_in[1];
    float* y = (float*)d_out;

    const size_t slab_h = (size_t)B_DIM * O_DIM * 2;              // 1 MB fp16
    const size_t xT_sz  = (size_t)B_DIM * I_DIM * sizeof(float);  // 2 MB
    const size_t wT_sz  = (size_t)O_DIM * I_DIM * sizeof(float);  // 4 MB
    const dim3 rgrid(B_DIM * O_DIM / 8 / 256);                    // 256 blocks
    const dim3 tgrid(I_DIM / 32, 512 / 32, 3);
    const dim3 tblk(32, 8);

    if (ws_size >= 16 * slab_h + xT_sz + wT_sz) {        // 22 MB
        _Float16* part = (_Float16*)d_ws;
        float* xT = (float*)((char*)d_ws + 16 * slab_h);
        float* wT = xT + (size_t)B_DIM * I_DIM;
        transpose3<<<tgrid, tblk, 0, stream>>>(x, xT, W, wT);
        trop_main<I_DIM / 16><<<dim3(8, 4, 16), 256, 0, stream>>>(xT, wT, part);
        trop_reduce_h<16><<<rgrid, 256, 0, stream>>>(part, y);
    } else if (ws_size >= 8 * slab_h + xT_sz + wT_sz) {  // 14 MB
        _Float16* part = (_Float16*)d_ws;
        float* xT = (float*)((char*)d_ws + 8 * slab_h);
        float* wT = xT + (size_t)B_DIM * I_DIM;
        transpose3<<<tgrid, tblk, 0, stream>>>(x, xT, W, wT);
        trop_main<I_DIM / 8><<<dim3(8, 4, 8), 256, 0, stream>>>(xT, wT, part);
        trop_reduce_h<8><<<rgrid, 256, 0, stream>>>(part, y);
    } else if (ws_size >= slab_h + xT_sz + wT_sz) {      // 7 MB: no K-split
        _Float16* part = (_Float16*)d_ws;
        float* xT = (float*)((char*)d_ws + slab_h);
        float* wT = xT + (size_t)B_DIM * I_DIM;
        transpose3<<<tgrid, tblk, 0, stream>>>(x, xT, W, wT);
        trop_main<I_DIM><<<dim3(8, 4, 1), 256, 0, stream>>>(xT, wT, part);
        trop_reduce_h<1><<<rgrid, 256, 0, stream>>>(part, y);
    } else {
        trop_naive<<<dim3(B_DIM * O_DIM / 256), 256, 0, stream>>>(x, W, y);
    }
}